// Round 1
// baseline (1080.085 us; speedup 1.0000x reference)
//
#include <hip/hip_runtime.h>
#include <math.h>

#define NROWS 200704
#define DIM 512
#define NKM 32

// ---- workspace layout (offsets in 4-byte units) ----
#define OFF_RED0   0        // float[32]
#define OFF_RED1   32       // float[32]
#define OFF_RED2   64       // float[32]
#define OFF_CNT    96       // int[4]   rows per class
#define OFF_NP     100      // int[32]  per-prototype counts
#define OFF_LC     132      // int      compacted-list count
#define OFF_SUMGP  144      // float[32] sum_d g*pn
#define OFF_BP     176      // float[32] sum_d b*pn
#define OFF_SCAL   208      // float[3]: sum g^2, sum g*b, sum b^2
#define OFF_G2GB   224      // float2[512]: (g^2, g*b) per dim
#define OFF_PROTON 1248     // float[32][512] normalized protos
#define OFF_GPT    17632    // float[32][512] g[d]*pn[j][d]
#define OFF_RSTATS 34016    // float4[N]: mu, istd, invL, 0
#define OFF_E      836832   // float[N][8]: exp(score/eps) for gt class
#define OFF_FLAGS  2442464  // int[N]: gt | (correct?4:0)
#define OFF_LIST   2643168  // int[N]: packed (slot<<19)|row for correct rows
#define OFF_FPART  2843872  // float[256][32*512] block partials

__device__ __forceinline__ float block_reduce_sum(float v, float* sm) {
    int t = threadIdx.x;
    sm[t] = v; __syncthreads();
    #pragma unroll
    for (int o = 128; o > 0; o >>= 1) {
        if (t < o) sm[t] += sm[t + o];
        __syncthreads();
    }
    float r = sm[0]; __syncthreads();
    return r;
}

// ---- K0: normalize prototypes, build tables ----
__global__ __launch_bounds__(256) void k_prep(const float* __restrict__ protos,
                                              const float* __restrict__ g,
                                              const float* __restrict__ b,
                                              float* __restrict__ ws) {
    __shared__ float sm[256];
    int t = threadIdx.x, j = blockIdx.x;
    if (j < NKM) {
        const float* p = protos + j * DIM;
        float v = p[t] * p[t] + p[t + 256] * p[t + 256];
        float ss = block_reduce_sum(v, sm);
        float den = fmaxf(sqrtf(ss), 1e-12f);
        float sgp = 0.f, sbp = 0.f;
        for (int d = t; d < DIM; d += 256) {
            float pn = p[d] / den;
            ws[OFF_PROTON + j * DIM + d] = pn;
            float gp = g[d] * pn;
            ws[OFF_GPT + j * DIM + d] = gp;
            sgp += gp; sbp += b[d] * pn;
        }
        float s1 = block_reduce_sum(sgp, sm);
        float s2 = block_reduce_sum(sbp, sm);
        if (t == 0) { ws[OFF_SUMGP + j] = s1; ws[OFF_BP + j] = s2; }
    } else {
        float a = 0.f, c = 0.f, e = 0.f;
        for (int d = t; d < DIM; d += 256) {
            float gv = g[d], bv = b[d];
            ws[OFF_G2GB + 2 * d]     = gv * gv;
            ws[OFF_G2GB + 2 * d + 1] = gv * bv;
            a += gv * gv; c += gv * bv; e += bv * bv;
        }
        float s1 = block_reduce_sum(a, sm);
        float s2 = block_reduce_sum(c, sm);
        float s3 = block_reduce_sum(e, sm);
        if (t == 0) { ws[OFF_SCAL] = s1; ws[OFF_SCAL + 1] = s2; ws[OFF_SCAL + 2] = s3; }
    }
}

// ---- K1: fused LN + L2 + 32 dots + out_seg + exp-scores. 8 lanes per row. ----
__global__ __launch_bounds__(256) void k_main(const float* __restrict__ feats,
                                              const float* __restrict__ mg,
                                              const float* __restrict__ mb,
                                              const int* __restrict__ gt_seg,
                                              float* __restrict__ ws,
                                              float* __restrict__ out) {
    __shared__ float gpt[NKM * DIM];   // 64 KB, GPT[j][d]
    int t = threadIdx.x;
    {
        const float4* s4 = (const float4*)(ws + OFF_GPT);
        float4* d4 = (float4*)gpt;
        for (int i = t; i < NKM * DIM / 4; i += 256) d4[i] = s4[i];
    }
    __syncthreads();
    int lane = t & 63;
    int oct = lane >> 3, li = lane & 7;
    int row = blockIdx.x * 32 + (t >> 6) * 8 + oct;

    float sx = 0.f, sxx = 0.f, sxg2 = 0.f, sx2g2 = 0.f, sxgb = 0.f;
    float dj[NKM];
    #pragma unroll
    for (int j = 0; j < NKM; ++j) dj[j] = 0.f;

    const float* xrow = feats + (size_t)row * DIM;
    for (int c = 0; c < 16; ++c) {
        int d0 = c * 32 + li * 4;
        float4 x4 = *(const float4*)(xrow + d0);
        float4 gA = *(const float4*)(ws + OFF_G2GB + 2 * d0);      // g2[d0],gb[d0],g2[d0+1],gb[d0+1]
        float4 gB = *(const float4*)(ws + OFF_G2GB + 2 * d0 + 4);
        sx   += x4.x + x4.y + x4.z + x4.w;
        sxx  += x4.x * x4.x + x4.y * x4.y + x4.z * x4.z + x4.w * x4.w;
        sxg2 += x4.x * gA.x + x4.y * gA.z + x4.z * gB.x + x4.w * gB.z;
        sx2g2 += x4.x * x4.x * gA.x + x4.y * x4.y * gA.z + x4.z * x4.z * gB.x + x4.w * x4.w * gB.z;
        sxgb += x4.x * gA.y + x4.y * gA.w + x4.z * gB.y + x4.w * gB.w;
        #pragma unroll
        for (int j = 0; j < NKM; ++j) {
            float4 w = *(const float4*)(gpt + j * DIM + d0);
            dj[j] = fmaf(x4.x, w.x, fmaf(x4.y, w.y, fmaf(x4.z, w.z, fmaf(x4.w, w.w, dj[j]))));
        }
    }
    // butterfly over the 8 lanes of this row's octet
    #pragma unroll
    for (int m = 1; m <= 4; m <<= 1) {
        sx += __shfl_xor(sx, m, 64);
        sxx += __shfl_xor(sxx, m, 64);
        sxg2 += __shfl_xor(sxg2, m, 64);
        sx2g2 += __shfl_xor(sx2g2, m, 64);
        sxgb += __shfl_xor(sxgb, m, 64);
        #pragma unroll
        for (int j = 0; j < NKM; ++j) dj[j] += __shfl_xor(dj[j], m, 64);
    }
    float mu  = sx * (1.0f / DIM);
    float var = sxx * (1.0f / DIM) - mu * mu;
    float istd = 1.0f / sqrtf(var + 1e-5f);
    float sG2 = ws[OFF_SCAL], sGB = ws[OFF_SCAL + 1], sB2 = ws[OFF_SCAL + 2];
    float l2 = istd * istd * (sx2g2 - 2.0f * mu * sxg2 + mu * mu * sG2)
             + 2.0f * istd * (sxgb - mu * sGB) + sB2;
    float L = sqrtf(fmaxf(l2, 0.0f));
    float invL = 1.0f / fmaxf(L, 1e-12f);
    float aa = istd * invL;
    float sv[NKM];
    #pragma unroll
    for (int j = 0; j < NKM; ++j)
        sv[j] = aa * (dj[j] - mu * ws[OFF_SUMGP + j]) + invL * ws[OFF_BP + j];

    float om[4];
    #pragma unroll
    for (int k = 0; k < 4; ++k) {
        float m0 = sv[k * 8];
        #pragma unroll
        for (int m = 1; m < 8; ++m) m0 = fmaxf(m0, sv[k * 8 + m]);
        om[k] = m0;
    }
    float mu4 = 0.25f * (om[0] + om[1] + om[2] + om[3]);
    float e0 = om[0] - mu4, e1 = om[1] - mu4, e2 = om[2] - mu4, e3 = om[3] - mu4;
    float v4 = 0.25f * (e0 * e0 + e1 * e1 + e2 * e2 + e3 * e3);
    float is4 = 1.0f / sqrtf(v4 + 1e-5f);
    float o0 = e0 * is4 * mg[0] + mb[0];
    float o1 = e1 * is4 * mg[1] + mb[1];
    float o2 = e2 * is4 * mg[2] + mb[2];
    float o3 = e3 * is4 * mg[3] + mb[3];
    int pred = 0; float bo = o0;
    if (o1 > bo) { bo = o1; pred = 1; }
    if (o2 > bo) { bo = o2; pred = 2; }
    if (o3 > bo) { bo = o3; pred = 3; }
    int gt = gt_seg[row] & 3;
    if (li == 0) {
        *(float4*)(out + (size_t)row * 4) = make_float4(o0, o1, o2, o3);
        ((int*)ws)[OFF_FLAGS + row] = gt | ((pred == gt) ? 4 : 0);
        *(float4*)(ws + OFF_RSTATS + (size_t)row * 4) = make_float4(mu, istd, invL, 0.f);
        float ev[8];
        #pragma unroll
        for (int m = 0; m < 8; ++m) {
            float s = sv[m];
            s = (gt == 1) ? sv[8 + m]  : s;
            s = (gt == 2) ? sv[16 + m] : s;
            s = (gt == 3) ? sv[24 + m] : s;
            ev[m] = expf(s * 20.0f);
        }
        *(float4*)(ws + OFF_E + (size_t)row * 8)     = make_float4(ev[0], ev[1], ev[2], ev[3]);
        *(float4*)(ws + OFF_E + (size_t)row * 8 + 4) = make_float4(ev[4], ev[5], ev[6], ev[7]);
    }
}

// ---- K2a: column sums of e per class + class counts ----
__global__ __launch_bounds__(256) void k_red0(const int* __restrict__ gt_seg,
                                              float* __restrict__ ws) {
    __shared__ float lred[NKM];
    __shared__ int lcnt[4];
    int t = threadIdx.x;
    if (t < NKM) lred[t] = 0.f;
    if (t < 4) lcnt[t] = 0;
    __syncthreads();
    int row = blockIdx.x * 256 + t;
    int gt = gt_seg[row] & 3;
    float4 ea = *(const float4*)(ws + OFF_E + (size_t)row * 8);
    float4 eb = *(const float4*)(ws + OFF_E + (size_t)row * 8 + 4);
    atomicAdd(&lred[gt * 8 + 0], ea.x); atomicAdd(&lred[gt * 8 + 1], ea.y);
    atomicAdd(&lred[gt * 8 + 2], ea.z); atomicAdd(&lred[gt * 8 + 3], ea.w);
    atomicAdd(&lred[gt * 8 + 4], eb.x); atomicAdd(&lred[gt * 8 + 5], eb.y);
    atomicAdd(&lred[gt * 8 + 6], eb.z); atomicAdd(&lred[gt * 8 + 7], eb.w);
    atomicAdd(&lcnt[gt], 1);
    __syncthreads();
    if (t < NKM) atomicAdd(&ws[OFF_RED0 + t], lred[t]);
    if (t < 4) atomicAdd(&((int*)ws)[OFF_CNT + t], lcnt[t]);
}

// ---- K2b: sinkhorn iteration-2 column sums (t1 = sum e*r1) ----
__global__ __launch_bounds__(256) void k_red1(const int* __restrict__ gt_seg,
                                              float* __restrict__ ws) {
    __shared__ float S0p[4], Bk[4], a1[NKM], lred[NKM];
    int t = threadIdx.x;
    if (t < 4) {
        float s = 0.f;
        #pragma unroll
        for (int m = 0; m < 8; ++m) s += ws[OFF_RED0 + t * 8 + m];
        S0p[t] = fmaxf(s, 1e-30f);
        Bk[t] = fmaxf((float)((const int*)ws)[OFF_CNT + t], 1.0f);
    }
    if (t < NKM) lred[t] = 0.f;
    __syncthreads();
    if (t < NKM) {
        float col = ws[OFF_RED0 + t] / S0p[t >> 3];
        a1[t] = 1.0f / (fmaxf(col, 1e-30f) * 8.0f);
    }
    __syncthreads();
    int row = blockIdx.x * 256 + t;
    int gt = gt_seg[row] & 3;
    float4 ea = *(const float4*)(ws + OFF_E + (size_t)row * 8);
    float4 eb = *(const float4*)(ws + OFF_E + (size_t)row * 8 + 4);
    float ev[8] = {ea.x, ea.y, ea.z, ea.w, eb.x, eb.y, eb.z, eb.w};
    float dotv = 0.f;
    #pragma unroll
    for (int m = 0; m < 8; ++m) dotv += ev[m] * a1[gt * 8 + m];
    float row1 = dotv / S0p[gt];
    float r1 = 1.0f / (fmaxf(row1, 1e-30f) * Bk[gt]);
    #pragma unroll
    for (int m = 0; m < 8; ++m) atomicAdd(&lred[gt * 8 + m], ev[m] * r1);
    __syncthreads();
    if (t < NKM) atomicAdd(&ws[OFF_RED1 + t], lred[t]);
}

// ---- K2c: sinkhorn iteration-3 column sums (t2 = sum e*r1*r2) ----
__global__ __launch_bounds__(256) void k_red2(const int* __restrict__ gt_seg,
                                              float* __restrict__ ws) {
    __shared__ float S0p[4], Bk[4], a1[NKM], a2[NKM], lred[NKM];
    int t = threadIdx.x;
    if (t < 4) {
        float s = 0.f;
        #pragma unroll
        for (int m = 0; m < 8; ++m) s += ws[OFF_RED0 + t * 8 + m];
        S0p[t] = fmaxf(s, 1e-30f);
        Bk[t] = fmaxf((float)((const int*)ws)[OFF_CNT + t], 1.0f);
    }
    if (t < NKM) lred[t] = 0.f;
    __syncthreads();
    if (t < NKM) {
        float col = ws[OFF_RED0 + t] / S0p[t >> 3];
        a1[t] = 1.0f / (fmaxf(col, 1e-30f) * 8.0f);
    }
    __syncthreads();
    if (t < NKM) {
        float col2 = a1[t] * ws[OFF_RED1 + t] / S0p[t >> 3];
        a2[t] = 1.0f / (fmaxf(col2, 1e-30f) * 8.0f);
    }
    __syncthreads();
    int row = blockIdx.x * 256 + t;
    int gt = gt_seg[row] & 3;
    float4 ea = *(const float4*)(ws + OFF_E + (size_t)row * 8);
    float4 eb = *(const float4*)(ws + OFF_E + (size_t)row * 8 + 4);
    float ev[8] = {ea.x, ea.y, ea.z, ea.w, eb.x, eb.y, eb.z, eb.w};
    float dotv = 0.f;
    #pragma unroll
    for (int m = 0; m < 8; ++m) dotv += ev[m] * a1[gt * 8 + m];
    float row1 = dotv / S0p[gt];
    float r1 = 1.0f / (fmaxf(row1, 1e-30f) * Bk[gt]);
    float dot2 = 0.f;
    #pragma unroll
    for (int m = 0; m < 8; ++m) dot2 += ev[m] * a1[gt * 8 + m] * a2[gt * 8 + m];
    float row2 = dot2 / S0p[gt] * r1;
    float r2 = 1.0f / (fmaxf(row2, 1e-30f) * Bk[gt]);
    #pragma unroll
    for (int m = 0; m < 8; ++m) atomicAdd(&lred[gt * 8 + m], ev[m] * r1 * r2);
    __syncthreads();
    if (t < NKM) atomicAdd(&ws[OFF_RED2 + t], lred[t]);
}

// ---- K3: per-row argmax assignment + compact list of correct rows + counts ----
__global__ __launch_bounds__(256) void k_assign(float* __restrict__ ws) {
    __shared__ float S0p[4], Bk[4], a1[NKM], a2[NKM], F[NKM];
    __shared__ int ln[NKM], lbuf[256];
    __shared__ int lcnt, lbase;
    int t = threadIdx.x;
    if (t < 4) {
        float s = 0.f;
        #pragma unroll
        for (int m = 0; m < 8; ++m) s += ws[OFF_RED0 + t * 8 + m];
        S0p[t] = fmaxf(s, 1e-30f);
        Bk[t] = fmaxf((float)((const int*)ws)[OFF_CNT + t], 1.0f);
    }
    if (t < NKM) ln[t] = 0;
    if (t == 0) lcnt = 0;
    __syncthreads();
    if (t < NKM) {
        float col = ws[OFF_RED0 + t] / S0p[t >> 3];
        a1[t] = 1.0f / (fmaxf(col, 1e-30f) * 8.0f);
    }
    __syncthreads();
    if (t < NKM) {
        float col2 = a1[t] * ws[OFF_RED1 + t] / S0p[t >> 3];
        a2[t] = 1.0f / (fmaxf(col2, 1e-30f) * 8.0f);
    }
    __syncthreads();
    if (t < NKM) {
        float col3 = a1[t] * a2[t] * ws[OFF_RED2 + t] / S0p[t >> 3];
        float a3 = 1.0f / (fmaxf(col3, 1e-30f) * 8.0f);
        F[t] = a1[t] * a2[t] * a3;
    }
    __syncthreads();
    int row = blockIdx.x * 256 + t;
    int flag = ((const int*)ws)[OFF_FLAGS + row];
    if (flag & 4) {
        int gt = flag & 3;
        float4 ea = *(const float4*)(ws + OFF_E + (size_t)row * 8);
        float4 eb = *(const float4*)(ws + OFF_E + (size_t)row * 8 + 4);
        float ev[8] = {ea.x, ea.y, ea.z, ea.w, eb.x, eb.y, eb.z, eb.w};
        int js = 0; float bv = ev[0] * F[gt * 8];
        #pragma unroll
        for (int m = 1; m < 8; ++m) {
            float v = ev[m] * F[gt * 8 + m];
            if (v > bv) { bv = v; js = m; }
        }
        int slot = gt * 8 + js;
        atomicAdd(&ln[slot], 1);
        int pos = atomicAdd(&lcnt, 1);
        lbuf[pos] = row | (slot << 19);
    }
    __syncthreads();
    if (t == 0) lbase = atomicAdd(&((int*)ws)[OFF_LC], lcnt);
    __syncthreads();
    if (t < lcnt) ((int*)ws)[OFF_LIST + lbase + t] = lbuf[t];
    if (t < NKM && ln[t]) atomicAdd(&((int*)ws)[OFF_NP + t], ln[t]);
}

// ---- K4: aggregate _c of correct rows into per-block LDS partials ----
__global__ __launch_bounds__(256) void k_agg(const float* __restrict__ feats,
                                             const float* __restrict__ g,
                                             const float* __restrict__ b,
                                             float* __restrict__ ws) {
    __shared__ float fl[NKM * DIM];   // 64 KB, rotation-swizzled
    int t = threadIdx.x;
    for (int i = t; i < NKM * DIM; i += 256) fl[i] = 0.f;
    __syncthreads();
    int cnt = ((const int*)ws)[OFF_LC];
    const float4* gp = (const float4*)g;
    const float4* bp = (const float4*)b;
    for (int i = blockIdx.x * 256 + t; i < cnt; i += 256 * 256) {
        int en = ((const int*)ws)[OFF_LIST + i];
        int row = en & 0x7FFFF;
        int slot = en >> 19;
        float4 rs = *(const float4*)(ws + OFF_RSTATS + (size_t)row * 4);  // mu,istd,invL
        const float4* xp = (const float4*)(feats + (size_t)row * DIM);
        int sbase = slot * DIM;
        for (int c = 0; c < DIM / 4; ++c) {
            float4 x = xp[c], gg = gp[c], bb = bp[c];
            int d = c * 4;
            int hi = d & ~31;
            float c0 = ((x.x - rs.x) * rs.y * gg.x + bb.x) * rs.z;
            float c1 = ((x.y - rs.x) * rs.y * gg.y + bb.y) * rs.z;
            float c2 = ((x.z - rs.x) * rs.y * gg.z + bb.z) * rs.z;
            float c3 = ((x.w - rs.x) * rs.y * gg.w + bb.w) * rs.z;
            atomicAdd(&fl[sbase + hi + ((d + 0 + slot) & 31)], c0);
            atomicAdd(&fl[sbase + hi + ((d + 1 + slot) & 31)], c1);
            atomicAdd(&fl[sbase + hi + ((d + 2 + slot) & 31)], c2);
            atomicAdd(&fl[sbase + hi + ((d + 3 + slot) & 31)], c3);
        }
    }
    __syncthreads();
    float4* dst = (float4*)(ws + OFF_FPART + (size_t)blockIdx.x * (NKM * DIM));
    const float4* src = (const float4*)fl;
    for (int i = t; i < NKM * DIM / 4; i += 256) dst[i] = src[i];
}

// ---- K5: reduce partials, l2-normalize f, EMA update, final renormalize ----
__global__ __launch_bounds__(256) void k_final(float* __restrict__ ws,
                                               float* __restrict__ out) {
    __shared__ float sm[256];
    int t = threadIdx.x, j = blockIdx.x, k = j >> 3;
    int nj = ((const int*)ws)[OFF_NP + j];
    int ck = ((const int*)ws)[OFF_CNT + k];
    int nsum = 0;
    #pragma unroll
    for (int m = 0; m < 8; ++m) nsum += ((const int*)ws)[OFF_NP + k * 8 + m];
    int d0 = t, d1 = t + 256;
    int i0 = j * DIM + (d0 & ~31) + ((d0 + j) & 31);
    int i1 = j * DIM + (d1 & ~31) + ((d1 + j) & 31);
    float f0 = 0.f, f1 = 0.f;
    for (int p = 0; p < 256; ++p) {
        f0 += ws[OFF_FPART + p * (NKM * DIM) + i0];
        f1 += ws[OFF_FPART + p * (NKM * DIM) + i1];
    }
    float nf = block_reduce_sum(f0 * f0 + f1 * f1, sm);
    float fin = 1.0f / fmaxf(sqrtf(nf), 1e-12f);
    float pn0 = ws[OFF_PROTON + j * DIM + d0];
    float pn1 = ws[OFF_PROTON + j * DIM + d1];
    bool valid = (nj != 0) && (ck > 0) && (nsum > 0);
    float r0 = valid ? (0.999f * pn0 + 0.001f * (f0 * fin)) : pn0;
    float r1 = valid ? (0.999f * pn1 + 0.001f * (f1 * fin)) : pn1;
    float n2 = block_reduce_sum(r0 * r0 + r1 * r1, sm);
    float i2 = 1.0f / fmaxf(sqrtf(n2), 1e-12f);
    out[(size_t)NROWS * 4 + j * DIM + d0] = r0 * i2;
    out[(size_t)NROWS * 4 + j * DIM + d1] = r1 * i2;
}

extern "C" void kernel_launch(void* const* d_in, const int* in_sizes, int n_in,
                              void* d_out, int out_size, void* d_ws, size_t ws_size,
                              hipStream_t stream) {
    const float* feats = (const float*)d_in[0];
    const float* ln_g  = (const float*)d_in[1];
    const float* ln_b  = (const float*)d_in[2];
    const float* mg    = (const float*)d_in[3];
    const float* mb    = (const float*)d_in[4];
    const float* prot  = (const float*)d_in[5];
    const int*   gt    = (const int*)d_in[6];
    float* out = (float*)d_out;
    float* ws  = (float*)d_ws;

    hipMemsetAsync(d_ws, 0, 576, stream);                       // zero accumulators
    k_prep<<<33, 256, 0, stream>>>(prot, ln_g, ln_b, ws);
    k_main<<<NROWS / 32, 256, 0, stream>>>(feats, mg, mb, gt, ws, out);
    k_red0<<<NROWS / 256, 256, 0, stream>>>(gt, ws);
    k_red1<<<NROWS / 256, 256, 0, stream>>>(gt, ws);
    k_red2<<<NROWS / 256, 256, 0, stream>>>(gt, ws);
    k_assign<<<NROWS / 256, 256, 0, stream>>>(ws);
    k_agg<<<256, 256, 0, stream>>>(feats, ln_g, ln_b, ws);
    k_final<<<NKM, 256, 0, stream>>>(ws, out);
}

// Round 2
// 802.181 us; speedup vs baseline: 1.3464x; 1.3464x over previous
//
#include <hip/hip_runtime.h>
#include <math.h>

#define NROWS 200704
#define DIM 512
#define NKM 32

// ---- workspace layout (offsets in 4-byte units) ----
#define OFF_RED0   0        // float[32]
#define OFF_RED1   32       // float[32]
#define OFF_RED2   64       // float[32]
#define OFF_CNT    96       // int[4]   rows per class
#define OFF_NP     100      // int[32]  per-prototype correct counts
#define OFF_CUR    192      // int[32*64] padded scatter cursors
#define OFF_BASE   2240     // int[32]  prefix bases
#define OFF_FACC   2304     // float[32*512] f accumulators
#define ZERO_FLOATS 18688   // memset range: everything above
#define OFF_SUMGP  18688    // float[32] sum_d g*pn
#define OFF_BP     18720    // float[32] sum_d b*pn
#define OFF_SCAL   18752    // float[3]: sum g^2, sum g*b, sum b^2
#define OFF_G2GB   18816    // float2[512]: (g^2, g*b) per dim
#define OFF_PROTON 19840    // float[32][512] normalized protos
#define OFF_GPT    36224    // float[32][512] g[d]*pn[j][d]
#define OFF_RSTATS 52608    // float4[N]: mu, istd, invL, 0
#define OFF_E      855424   // float[N][8]: exp(score/eps) for gt class
#define OFF_FLAGS  2461056  // int[N]: gt|(correct?4:0), later slot or -1
#define OFF_SORT   2661760  // int[N]: rows sorted by slot

__device__ __forceinline__ float block_reduce_sum(float v, float* sm) {
    int t = threadIdx.x;
    sm[t] = v; __syncthreads();
    #pragma unroll
    for (int o = 128; o > 0; o >>= 1) {
        if (t < o) sm[t] += sm[t + o];
        __syncthreads();
    }
    float r = sm[0]; __syncthreads();
    return r;
}

// ---- K0: normalize prototypes, build tables ----
__global__ __launch_bounds__(256) void k_prep(const float* __restrict__ protos,
                                              const float* __restrict__ g,
                                              const float* __restrict__ b,
                                              float* __restrict__ ws) {
    __shared__ float sm[256];
    int t = threadIdx.x, j = blockIdx.x;
    if (j < NKM) {
        const float* p = protos + j * DIM;
        float v = p[t] * p[t] + p[t + 256] * p[t + 256];
        float ss = block_reduce_sum(v, sm);
        float den = fmaxf(sqrtf(ss), 1e-12f);
        float sgp = 0.f, sbp = 0.f;
        for (int d = t; d < DIM; d += 256) {
            float pn = p[d] / den;
            ws[OFF_PROTON + j * DIM + d] = pn;
            float gp = g[d] * pn;
            ws[OFF_GPT + j * DIM + d] = gp;
            sgp += gp; sbp += b[d] * pn;
        }
        float s1 = block_reduce_sum(sgp, sm);
        float s2 = block_reduce_sum(sbp, sm);
        if (t == 0) { ws[OFF_SUMGP + j] = s1; ws[OFF_BP + j] = s2; }
    } else {
        float a = 0.f, c = 0.f, e = 0.f;
        for (int d = t; d < DIM; d += 256) {
            float gv = g[d], bv = b[d];
            ws[OFF_G2GB + 2 * d]     = gv * gv;
            ws[OFF_G2GB + 2 * d + 1] = gv * bv;
            a += gv * gv; c += gv * bv; e += bv * bv;
        }
        float s1 = block_reduce_sum(a, sm);
        float s2 = block_reduce_sum(c, sm);
        float s3 = block_reduce_sum(e, sm);
        if (t == 0) { ws[OFF_SCAL] = s1; ws[OFF_SCAL + 1] = s2; ws[OFF_SCAL + 2] = s3; }
    }
}

// ---- K1: fused LN + L2 + 32 dots. 8 lanes x 4 rows per octet. ----
#define STATS(XR, r) { \
    float _a = XR.x, _b = XR.y, _c = XR.z, _d = XR.w; \
    sx[r] += _a + _b + _c + _d; \
    float _a2 = _a * _a, _b2 = _b * _b, _c2 = _c * _c, _d2 = _d * _d; \
    sxx[r] += _a2 + _b2 + _c2 + _d2; \
    sxg2[r]  = fmaf(_a, gA.x, fmaf(_b, gA.z, fmaf(_c, gB.x, fmaf(_d, gB.z, sxg2[r])))); \
    sx2g2[r] = fmaf(_a2, gA.x, fmaf(_b2, gA.z, fmaf(_c2, gB.x, fmaf(_d2, gB.z, sx2g2[r])))); \
    sxgb[r]  = fmaf(_a, gA.y, fmaf(_b, gA.w, fmaf(_c, gB.y, fmaf(_d, gB.w, sxgb[r])))); \
}

#define EPILOGUE(DJ, r) { \
    float a_sx = sx[r], a_sxx = sxx[r], a_sxg2 = sxg2[r], a_sx2g2 = sx2g2[r], a_sxgb = sxgb[r]; \
    _Pragma("unroll") \
    for (int m = 1; m <= 4; m <<= 1) { \
        a_sx += __shfl_xor(a_sx, m, 64); \
        a_sxx += __shfl_xor(a_sxx, m, 64); \
        a_sxg2 += __shfl_xor(a_sxg2, m, 64); \
        a_sx2g2 += __shfl_xor(a_sx2g2, m, 64); \
        a_sxgb += __shfl_xor(a_sxgb, m, 64); \
        _Pragma("unroll") \
        for (int j = 0; j < NKM; ++j) DJ[j] += __shfl_xor(DJ[j], m, 64); \
    } \
    float mu = a_sx * (1.0f / DIM); \
    float var = a_sxx * (1.0f / DIM) - mu * mu; \
    float istd = 1.0f / sqrtf(var + 1e-5f); \
    float l2 = istd * istd * (a_sx2g2 - 2.0f * mu * a_sxg2 + mu * mu * s_scal[0]) \
             + 2.0f * istd * (a_sxgb - mu * s_scal[1]) + s_scal[2]; \
    float L = sqrtf(fmaxf(l2, 0.0f)); \
    float invL = 1.0f / fmaxf(L, 1e-12f); \
    float aa = istd * invL; \
    _Pragma("unroll") \
    for (int j = 0; j < NKM; ++j) DJ[j] = aa * (DJ[j] - mu * s_sumgp[j]) + invL * s_bp[j]; \
    float om[4]; \
    _Pragma("unroll") \
    for (int k = 0; k < 4; ++k) { \
        float m0 = DJ[k * 8]; \
        _Pragma("unroll") \
        for (int m = 1; m < 8; ++m) m0 = fmaxf(m0, DJ[k * 8 + m]); \
        om[k] = m0; \
    } \
    float mu4 = 0.25f * (om[0] + om[1] + om[2] + om[3]); \
    float e0 = om[0] - mu4, e1 = om[1] - mu4, e2 = om[2] - mu4, e3 = om[3] - mu4; \
    float v4 = 0.25f * (e0 * e0 + e1 * e1 + e2 * e2 + e3 * e3); \
    float is4 = 1.0f / sqrtf(v4 + 1e-5f); \
    float o0 = e0 * is4 * mg[0] + mb[0]; \
    float o1 = e1 * is4 * mg[1] + mb[1]; \
    float o2 = e2 * is4 * mg[2] + mb[2]; \
    float o3 = e3 * is4 * mg[3] + mb[3]; \
    int pred = 0; float bo = o0; \
    if (o1 > bo) { bo = o1; pred = 1; } \
    if (o2 > bo) { bo = o2; pred = 2; } \
    if (o3 > bo) { bo = o3; pred = 3; } \
    int row = row0 + r; \
    int gtv = gt_seg[row] & 3; \
    if (li == 0) { \
        *(float4*)(out + (size_t)row * 4) = make_float4(o0, o1, o2, o3); \
        ((int*)ws)[OFF_FLAGS + row] = gtv | ((pred == gtv) ? 4 : 0); \
        *(float4*)(ws + OFF_RSTATS + (size_t)row * 4) = make_float4(mu, istd, invL, 0.f); \
        float ev[8]; \
        _Pragma("unroll") \
        for (int m = 0; m < 8; ++m) { \
            float s = DJ[m]; \
            s = (gtv == 1) ? DJ[8 + m]  : s; \
            s = (gtv == 2) ? DJ[16 + m] : s; \
            s = (gtv == 3) ? DJ[24 + m] : s; \
            ev[m] = expf(s * 20.0f); \
        } \
        *(float4*)(ws + OFF_E + (size_t)row * 8)     = make_float4(ev[0], ev[1], ev[2], ev[3]); \
        *(float4*)(ws + OFF_E + (size_t)row * 8 + 4) = make_float4(ev[4], ev[5], ev[6], ev[7]); \
    } \
}

__global__ __launch_bounds__(256, 2) void k_main(const float* __restrict__ feats,
                                                 const float* __restrict__ mg,
                                                 const float* __restrict__ mb,
                                                 const int* __restrict__ gt_seg,
                                                 float* __restrict__ ws,
                                                 float* __restrict__ out) {
    __shared__ float gpt[NKM * DIM];   // 64 KB
    __shared__ float s_sumgp[NKM], s_bp[NKM], s_scal[3];
    int t = threadIdx.x;
    {
        const float4* s4 = (const float4*)(ws + OFF_GPT);
        float4* d4 = (float4*)gpt;
        #pragma unroll 4
        for (int i = t; i < NKM * DIM / 4; i += 256) d4[i] = s4[i];
        if (t < NKM) { s_sumgp[t] = ws[OFF_SUMGP + t]; s_bp[t] = ws[OFF_BP + t]; }
        if (t < 3) s_scal[t] = ws[OFF_SCAL + t];
    }
    __syncthreads();
    int lane = t & 63, wv = t >> 6;
    int oct = lane >> 3, li = lane & 7;
    int row0 = blockIdx.x * 128 + wv * 32 + oct * 4;
    const float* xb = feats + (size_t)row0 * DIM;

    float dj0[NKM], dj1[NKM], dj2[NKM], dj3[NKM];
    #pragma unroll
    for (int j = 0; j < NKM; ++j) { dj0[j] = 0.f; dj1[j] = 0.f; dj2[j] = 0.f; dj3[j] = 0.f; }
    float sx[4] = {0,0,0,0}, sxx[4] = {0,0,0,0}, sxg2[4] = {0,0,0,0};
    float sx2g2[4] = {0,0,0,0}, sxgb[4] = {0,0,0,0};

    for (int c = 0; c < 16; ++c) {
        int d0 = c * 32 + li * 4;
        float4 x0 = *(const float4*)(xb + d0);
        float4 x1 = *(const float4*)(xb + DIM + d0);
        float4 x2 = *(const float4*)(xb + 2 * DIM + d0);
        float4 x3 = *(const float4*)(xb + 3 * DIM + d0);
        float4 gA = *(const float4*)(ws + OFF_G2GB + 2 * d0);
        float4 gB = *(const float4*)(ws + OFF_G2GB + 2 * d0 + 4);
        STATS(x0, 0) STATS(x1, 1) STATS(x2, 2) STATS(x3, 3)
        #pragma unroll
        for (int j = 0; j < NKM; ++j) {
            float4 w = *(const float4*)(gpt + j * DIM + d0);
            dj0[j] = fmaf(x0.x, w.x, fmaf(x0.y, w.y, fmaf(x0.z, w.z, fmaf(x0.w, w.w, dj0[j]))));
            dj1[j] = fmaf(x1.x, w.x, fmaf(x1.y, w.y, fmaf(x1.z, w.z, fmaf(x1.w, w.w, dj1[j]))));
            dj2[j] = fmaf(x2.x, w.x, fmaf(x2.y, w.y, fmaf(x2.z, w.z, fmaf(x2.w, w.w, dj2[j]))));
            dj3[j] = fmaf(x3.x, w.x, fmaf(x3.y, w.y, fmaf(x3.z, w.z, fmaf(x3.w, w.w, dj3[j]))));
        }
    }
    EPILOGUE(dj0, 0)
    EPILOGUE(dj1, 1)
    EPILOGUE(dj2, 2)
    EPILOGUE(dj3, 3)
}

// ---- K2a: column sums of e per class + class counts ----
__global__ __launch_bounds__(256) void k_red0(const int* __restrict__ gt_seg,
                                              float* __restrict__ ws) {
    __shared__ float lred[NKM];
    __shared__ int lcnt[4];
    int t = threadIdx.x;
    if (t < NKM) lred[t] = 0.f;
    if (t < 4) lcnt[t] = 0;
    __syncthreads();
    int row = blockIdx.x * 256 + t;
    int gt = gt_seg[row] & 3;
    float4 ea = *(const float4*)(ws + OFF_E + (size_t)row * 8);
    float4 eb = *(const float4*)(ws + OFF_E + (size_t)row * 8 + 4);
    atomicAdd(&lred[gt * 8 + 0], ea.x); atomicAdd(&lred[gt * 8 + 1], ea.y);
    atomicAdd(&lred[gt * 8 + 2], ea.z); atomicAdd(&lred[gt * 8 + 3], ea.w);
    atomicAdd(&lred[gt * 8 + 4], eb.x); atomicAdd(&lred[gt * 8 + 5], eb.y);
    atomicAdd(&lred[gt * 8 + 6], eb.z); atomicAdd(&lred[gt * 8 + 7], eb.w);
    atomicAdd(&lcnt[gt], 1);
    __syncthreads();
    if (t < NKM) atomicAdd(&ws[OFF_RED0 + t], lred[t]);
    if (t < 4) atomicAdd(&((int*)ws)[OFF_CNT + t], lcnt[t]);
}

// ---- K2b: sinkhorn iteration-2 column sums ----
__global__ __launch_bounds__(256) void k_red1(const int* __restrict__ gt_seg,
                                              float* __restrict__ ws) {
    __shared__ float S0p[4], Bk[4], a1[NKM], lred[NKM];
    int t = threadIdx.x;
    if (t < 4) {
        float s = 0.f;
        #pragma unroll
        for (int m = 0; m < 8; ++m) s += ws[OFF_RED0 + t * 8 + m];
        S0p[t] = fmaxf(s, 1e-30f);
        Bk[t] = fmaxf((float)((const int*)ws)[OFF_CNT + t], 1.0f);
    }
    if (t < NKM) lred[t] = 0.f;
    __syncthreads();
    if (t < NKM) {
        float col = ws[OFF_RED0 + t] / S0p[t >> 3];
        a1[t] = 1.0f / (fmaxf(col, 1e-30f) * 8.0f);
    }
    __syncthreads();
    int row = blockIdx.x * 256 + t;
    int gt = gt_seg[row] & 3;
    float4 ea = *(const float4*)(ws + OFF_E + (size_t)row * 8);
    float4 eb = *(const float4*)(ws + OFF_E + (size_t)row * 8 + 4);
    float ev[8] = {ea.x, ea.y, ea.z, ea.w, eb.x, eb.y, eb.z, eb.w};
    float dotv = 0.f;
    #pragma unroll
    for (int m = 0; m < 8; ++m) dotv += ev[m] * a1[gt * 8 + m];
    float row1 = dotv / S0p[gt];
    float r1 = 1.0f / (fmaxf(row1, 1e-30f) * Bk[gt]);
    #pragma unroll
    for (int m = 0; m < 8; ++m) atomicAdd(&lred[gt * 8 + m], ev[m] * r1);
    __syncthreads();
    if (t < NKM) atomicAdd(&ws[OFF_RED1 + t], lred[t]);
}

// ---- K2c: sinkhorn iteration-3 column sums ----
__global__ __launch_bounds__(256) void k_red2(const int* __restrict__ gt_seg,
                                              float* __restrict__ ws) {
    __shared__ float S0p[4], Bk[4], a1[NKM], a2[NKM], lred[NKM];
    int t = threadIdx.x;
    if (t < 4) {
        float s = 0.f;
        #pragma unroll
        for (int m = 0; m < 8; ++m) s += ws[OFF_RED0 + t * 8 + m];
        S0p[t] = fmaxf(s, 1e-30f);
        Bk[t] = fmaxf((float)((const int*)ws)[OFF_CNT + t], 1.0f);
    }
    if (t < NKM) lred[t] = 0.f;
    __syncthreads();
    if (t < NKM) {
        float col = ws[OFF_RED0 + t] / S0p[t >> 3];
        a1[t] = 1.0f / (fmaxf(col, 1e-30f) * 8.0f);
    }
    __syncthreads();
    if (t < NKM) {
        float col2 = a1[t] * ws[OFF_RED1 + t] / S0p[t >> 3];
        a2[t] = 1.0f / (fmaxf(col2, 1e-30f) * 8.0f);
    }
    __syncthreads();
    int row = blockIdx.x * 256 + t;
    int gt = gt_seg[row] & 3;
    float4 ea = *(const float4*)(ws + OFF_E + (size_t)row * 8);
    float4 eb = *(const float4*)(ws + OFF_E + (size_t)row * 8 + 4);
    float ev[8] = {ea.x, ea.y, ea.z, ea.w, eb.x, eb.y, eb.z, eb.w};
    float dotv = 0.f;
    #pragma unroll
    for (int m = 0; m < 8; ++m) dotv += ev[m] * a1[gt * 8 + m];
    float row1 = dotv / S0p[gt];
    float r1 = 1.0f / (fmaxf(row1, 1e-30f) * Bk[gt]);
    float dot2 = 0.f;
    #pragma unroll
    for (int m = 0; m < 8; ++m) dot2 += ev[m] * a1[gt * 8 + m] * a2[gt * 8 + m];
    float row2 = dot2 / S0p[gt] * r1;
    float r2 = 1.0f / (fmaxf(row2, 1e-30f) * Bk[gt]);
    #pragma unroll
    for (int m = 0; m < 8; ++m) atomicAdd(&lred[gt * 8 + m], ev[m] * r1 * r2);
    __syncthreads();
    if (t < NKM) atomicAdd(&ws[OFF_RED2 + t], lred[t]);
}

// ---- K3: per-row argmax assignment -> slot (or -1) + per-slot counts ----
__global__ __launch_bounds__(256) void k_assign(float* __restrict__ ws) {
    __shared__ float S0p[4], Bk[4], a1[NKM], a2[NKM], F[NKM];
    __shared__ int ln[NKM];
    int t = threadIdx.x;
    if (t < 4) {
        float s = 0.f;
        #pragma unroll
        for (int m = 0; m < 8; ++m) s += ws[OFF_RED0 + t * 8 + m];
        S0p[t] = fmaxf(s, 1e-30f);
        Bk[t] = fmaxf((float)((const int*)ws)[OFF_CNT + t], 1.0f);
    }
    if (t < NKM) ln[t] = 0;
    __syncthreads();
    if (t < NKM) {
        float col = ws[OFF_RED0 + t] / S0p[t >> 3];
        a1[t] = 1.0f / (fmaxf(col, 1e-30f) * 8.0f);
    }
    __syncthreads();
    if (t < NKM) {
        float col2 = a1[t] * ws[OFF_RED1 + t] / S0p[t >> 3];
        a2[t] = 1.0f / (fmaxf(col2, 1e-30f) * 8.0f);
    }
    __syncthreads();
    if (t < NKM) {
        float col3 = a1[t] * a2[t] * ws[OFF_RED2 + t] / S0p[t >> 3];
        float a3 = 1.0f / (fmaxf(col3, 1e-30f) * 8.0f);
        F[t] = a1[t] * a2[t] * a3;
    }
    __syncthreads();
    int row = blockIdx.x * 256 + t;
    int flag = ((const int*)ws)[OFF_FLAGS + row];
    int slotv = -1;
    if (flag & 4) {
        int gt = flag & 3;
        float4 ea = *(const float4*)(ws + OFF_E + (size_t)row * 8);
        float4 eb = *(const float4*)(ws + OFF_E + (size_t)row * 8 + 4);
        float ev[8] = {ea.x, ea.y, ea.z, ea.w, eb.x, eb.y, eb.z, eb.w};
        int js = 0; float bv = ev[0] * F[gt * 8];
        #pragma unroll
        for (int m = 1; m < 8; ++m) {
            float v = ev[m] * F[gt * 8 + m];
            if (v > bv) { bv = v; js = m; }
        }
        slotv = gt * 8 + js;
        atomicAdd(&ln[slotv], 1);
    }
    ((int*)ws)[OFF_FLAGS + row] = slotv;   // overwrite with slot / -1
    __syncthreads();
    if (t < NKM && ln[t]) atomicAdd(&((int*)ws)[OFF_NP + t], ln[t]);
}

// ---- K3b: prefix of NP -> BASE ----
__global__ void k_prefix(float* __restrict__ ws) {
    if (threadIdx.x == 0) {
        int acc = 0;
        for (int s = 0; s < NKM; ++s) {
            ((int*)ws)[OFF_BASE + s] = acc;
            acc += ((const int*)ws)[OFF_NP + s];
        }
    }
}

// ---- K3c: scatter rows into slot-sorted list ----
__global__ __launch_bounds__(256) void k_scatter(float* __restrict__ ws) {
    int row = blockIdx.x * 256 + threadIdx.x;
    int s = ((const int*)ws)[OFF_FLAGS + row];
    if (s >= 0) {
        int pos = atomicAdd(&((int*)ws)[OFF_CUR + s * 64], 1);
        ((int*)ws)[OFF_SORT + ((const int*)ws)[OFF_BASE + s] + pos] = row;
    }
}

// ---- K4: aggregate _c over sorted slot lists, register accumulation ----
__global__ __launch_bounds__(256) void k_agg(const float* __restrict__ feats,
                                             const float* __restrict__ g,
                                             const float* __restrict__ b,
                                             float* __restrict__ ws) {
    int t = threadIdx.x;
    int slot = blockIdx.x >> 4, ch = blockIdx.x & 15;
    int n = ((const int*)ws)[OFF_NP + slot];
    int base = ((const int*)ws)[OFF_BASE + slot];
    int r0 = base + (ch * n) / 16;
    int r1 = base + ((ch + 1) * n) / 16;
    if (r0 >= r1) return;
    const int* sortl = (const int*)ws + OFF_SORT;
    float2 gv = *(const float2*)(g + 2 * t);
    float2 bv = *(const float2*)(b + 2 * t);
    float acc0 = 0.f, acc1 = 0.f;
    #pragma unroll 4
    for (int i = r0; i < r1; ++i) {
        int row = sortl[i];
        float4 rs = *(const float4*)(ws + OFF_RSTATS + (size_t)row * 4); // mu,istd,invL
        float2 x = *(const float2*)(feats + (size_t)row * DIM + 2 * t);
        acc0 += ((x.x - rs.x) * rs.y * gv.x + bv.x) * rs.z;
        acc1 += ((x.y - rs.x) * rs.y * gv.y + bv.y) * rs.z;
    }
    atomicAdd(&ws[OFF_FACC + slot * DIM + 2 * t],     acc0);
    atomicAdd(&ws[OFF_FACC + slot * DIM + 2 * t + 1], acc1);
}

// ---- K5: l2-normalize f, EMA update, final renormalize ----
__global__ __launch_bounds__(256) void k_final(float* __restrict__ ws,
                                               float* __restrict__ out) {
    __shared__ float sm[256];
    int t = threadIdx.x, j = blockIdx.x, k = j >> 3;
    int nj = ((const int*)ws)[OFF_NP + j];
    int ck = ((const int*)ws)[OFF_CNT + k];
    int nsum = 0;
    #pragma unroll
    for (int m = 0; m < 8; ++m) nsum += ((const int*)ws)[OFF_NP + k * 8 + m];
    int d0 = t, d1 = t + 256;
    float f0 = ws[OFF_FACC + j * DIM + d0];
    float f1 = ws[OFF_FACC + j * DIM + d1];
    float nf = block_reduce_sum(f0 * f0 + f1 * f1, sm);
    float fin = 1.0f / fmaxf(sqrtf(nf), 1e-12f);
    float pn0 = ws[OFF_PROTON + j * DIM + d0];
    float pn1 = ws[OFF_PROTON + j * DIM + d1];
    bool valid = (nj != 0) && (ck > 0) && (nsum > 0);
    float r0 = valid ? (0.999f * pn0 + 0.001f * (f0 * fin)) : pn0;
    float r1 = valid ? (0.999f * pn1 + 0.001f * (f1 * fin)) : pn1;
    float n2 = block_reduce_sum(r0 * r0 + r1 * r1, sm);
    float i2 = 1.0f / fmaxf(sqrtf(n2), 1e-12f);
    out[(size_t)NROWS * 4 + j * DIM + d0] = r0 * i2;
    out[(size_t)NROWS * 4 + j * DIM + d1] = r1 * i2;
}

extern "C" void kernel_launch(void* const* d_in, const int* in_sizes, int n_in,
                              void* d_out, int out_size, void* d_ws, size_t ws_size,
                              hipStream_t stream) {
    const float* feats = (const float*)d_in[0];
    const float* ln_g  = (const float*)d_in[1];
    const float* ln_b  = (const float*)d_in[2];
    const float* mg    = (const float*)d_in[3];
    const float* mb    = (const float*)d_in[4];
    const float* prot  = (const float*)d_in[5];
    const int*   gt    = (const int*)d_in[6];
    float* out = (float*)d_out;
    float* ws  = (float*)d_ws;

    hipMemsetAsync(d_ws, 0, ZERO_FLOATS * 4, stream);
    k_prep<<<33, 256, 0, stream>>>(prot, ln_g, ln_b, ws);
    k_main<<<NROWS / 128, 256, 0, stream>>>(feats, mg, mb, gt, ws, out);
    k_red0<<<NROWS / 256, 256, 0, stream>>>(gt, ws);
    k_red1<<<NROWS / 256, 256, 0, stream>>>(gt, ws);
    k_red2<<<NROWS / 256, 256, 0, stream>>>(gt, ws);
    k_assign<<<NROWS / 256, 256, 0, stream>>>(ws);
    k_prefix<<<1, 64, 0, stream>>>(ws);
    k_scatter<<<NROWS / 256, 256, 0, stream>>>(ws);
    k_agg<<<NKM * 16, 256, 0, stream>>>(feats, ln_g, ln_b, ws);
    k_final<<<NKM, 256, 0, stream>>>(ws, out);
}